// Round 7
// baseline (598.326 us; speedup 1.0000x reference)
//
#include <hip/hip_runtime.h>

// CRF forward (partition fn), B=512, T=512, L=102 (start=100, stop=101).
// R14: R13 + consumer-side R. R13 post-mortem: dur 298->265us, conflicts->0,
// but per-step ~1245cy is still ~1000cy stall. R13's serial path ended with
// wave_sum64 (6 dependent DPP) + S pad-write BEFORE the barrier every step.
// Fix: every lane reads ALL of Q in the dot phase anyway, so each lane
// computes R = sum q_{t-1} itself as a side-sum of its own reads (26 f32x4
// adds in 2 chains, issue hidden under read-stall shadow). rcp(R) finishes
// before the dot horizontal -> R fully off-path. DPP chain, S writes, and
// pad bookkeeping deleted. Path: reads -> dots -> 2 muls -> write -> barrier.
// log2/Lacc + logit prefetch moved AFTER the barrier (overlap next reads).
// Linear recurrence (same math):
//   Q_t[j] = E_j(t) * sum_k Mhat[j,k] Q_{t-1}[k] * rcp(R)*2^-8
// Verification handles: VGPR ~140-160 (132 + ~700us => spilled), LDS ~1KB,
// conflicts 0.

typedef float f32x2 __attribute__((ext_vector_type(2)));
typedef float f32x4 __attribute__((ext_vector_type(4)));

#define CRF_L 102
#define CRF_RP 104
#define CRF_START 100
#define CRF_STOP 101
#define NEG_BIG (-1.0e30f)
#define LN2F 0.6931471805599453f

#define REP25(X) X(0) X(1) X(2) X(3) X(4) X(5) X(6) X(7) X(8) X(9) X(10) \
                 X(11) X(12) X(13) X(14) X(15) X(16) X(17) X(18) X(19) \
                 X(20) X(21) X(22) X(23) X(24)

template <int CTRL>
__device__ __forceinline__ float dpp_add_step(float x) {
    int xi = __builtin_bit_cast(int, x);
    int yi = __builtin_amdgcn_update_dpp(0, xi, CTRL, 0xf, 0xf, true);
    return x + __builtin_bit_cast(float, yi);
}
__device__ __forceinline__ float wave_sum64(float v) {
    v = dpp_add_step<0x111>(v);  // row_shr:1
    v = dpp_add_step<0x112>(v);  // row_shr:2
    v = dpp_add_step<0x114>(v);  // row_shr:4
    v = dpp_add_step<0x118>(v);  // row_shr:8
    v = dpp_add_step<0x142>(v);  // row_bcast:15
    v = dpp_add_step<0x143>(v);  // row_bcast:31
    return __builtin_bit_cast(float,
        __builtin_amdgcn_readlane(__builtin_bit_cast(int, v), 63));
}

__device__ __forceinline__ f32x2 mk2f(const float* rowp, int k, float rmx) {
    float e0 = __expf(rowp[k + 0] - rmx);
    float e1 = __expf(rowp[k + 1] - rmx);
    return (f32x2){e0, e1};
}

__attribute__((amdgpu_waves_per_eu(1, 1)))
__launch_bounds__(128)
__global__ void crf_forward_kernel(const float* __restrict__ logits,
                                   const float* __restrict__ trans,
                                   const int* __restrict__ lens,
                                   float* __restrict__ out,
                                   int B, int T) {
    const int b    = blockIdx.x;
    const int tid  = threadIdx.x;          // 0..127
    const int wv   = tid >> 6;             // wave 0/1
    const int lane = tid & 63;
    const bool active = (lane < 51);
    const int r    = 51 * wv + lane;       // row 0..101 for active lanes

    // Q double-buffer: [p][0..101] = q values; [p][102],[103] = 0 (pad, const)
    __shared__ __align__(16) float Qbuf[2][CRF_RP];

    // ---- init Qbuf[0] = onehot(START); pads of BOTH buffers = 0 ----
    if (tid < 51) {
        int i0 = 2 * tid;
        Qbuf[0][i0]     = (i0 == CRF_START) ? 1.f : 0.f;
        Qbuf[0][i0 + 1] = 0.f;
    }
    if (tid == 0) {
        Qbuf[0][102] = 0.f; Qbuf[0][103] = 0.f;
        Qbuf[1][102] = 0.f; Qbuf[1][103] = 0.f;
    }

    // ---- per-lane row of Mhat = exp(trans[r,:] - rowmax) in 51 f32x2 regs --
    const float* rowp = trans + (size_t)CRF_L * (active ? r : 0);
    float rmx = NEG_BIG;
    #pragma unroll
    for (int k = 0; k < CRF_L; ++k) rmx = fmaxf(rmx, rowp[k]);

#define DECLM(j) f32x2 m##j##a, m##j##b;
    REP25(DECLM)
#undef DECLM
    f32x2 m25a;
#define PACKJ(j) m##j##a = mk2f(rowp, 4*(j), rmx); \
                 m##j##b = mk2f(rowp, 4*(j)+2, rmx);
    REP25(PACKJ)
#undef PACKJ
    m25a = mk2f(rowp, 100, rmx);           // k = 100,101 (pads have no coeff)

    // E = exp(logit + rmx); inactive lanes forced to 0 via -inf bias
    const float erm = active ? rmx : NEG_BIG;

    const int len = min(lens[b], T);
    const float* lgp = logits + (size_t)b * (size_t)T * (size_t)CRF_L
                              + (active ? r : 0);

    // depth-3 scalar logit prefetch
    float lgA = lgp[0];
    float lgB = lgp[(size_t)min(1, T - 1) * CRF_L];
    float lgC = lgp[(size_t)min(2, T - 1) * CRF_L];

    float q    = 0.f;
    float Lacc = 0.f;

    __syncthreads();                       // init visible to both waves

    for (int t = 0; t < len; ++t) {
        const int cur = t & 1;
        const f32x4* P4 = reinterpret_cast<const f32x4*>(&Qbuf[cur][0]);

        // ---- dot(Mhat[r,:], Q) + side-sum R, all from the same 26 b128 ----
        f32x2 aL0 = {0.f,0.f}, aL1 = {0.f,0.f}, aL2 = {0.f,0.f}, aL3 = {0.f,0.f};
        f32x2 aH0 = {0.f,0.f}, aH1 = {0.f,0.f}, aH2 = {0.f,0.f}, aH3 = {0.f,0.f};
        f32x4 rs0 = {0.f,0.f,0.f,0.f}, rs1 = {0.f,0.f,0.f,0.f};
#define DOTQ(j, AL, AH, RS) { f32x4 qv_ = P4[j]; \
        RS += qv_; \
        AL = __builtin_elementwise_fma(m##j##a, (f32x2){qv_[0], qv_[1]}, AL); \
        AH = __builtin_elementwise_fma(m##j##b, (f32x2){qv_[2], qv_[3]}, AH); }
        DOTQ(0,  aL0, aH0, rs0) DOTQ(1,  aL1, aH1, rs1)
        DOTQ(2,  aL2, aH2, rs0) DOTQ(3,  aL3, aH3, rs1)
        DOTQ(4,  aL0, aH0, rs0) DOTQ(5,  aL1, aH1, rs1)
        DOTQ(6,  aL2, aH2, rs0) DOTQ(7,  aL3, aH3, rs1)
        DOTQ(8,  aL0, aH0, rs0) DOTQ(9,  aL1, aH1, rs1)
        DOTQ(10, aL2, aH2, rs0) DOTQ(11, aL3, aH3, rs1)
        DOTQ(12, aL0, aH0, rs0) DOTQ(13, aL1, aH1, rs1)
        DOTQ(14, aL2, aH2, rs0) DOTQ(15, aL3, aH3, rs1)
        DOTQ(16, aL0, aH0, rs0) DOTQ(17, aL1, aH1, rs1)
        DOTQ(18, aL2, aH2, rs0) DOTQ(19, aL3, aH3, rs1)
        DOTQ(20, aL0, aH0, rs0) DOTQ(21, aL1, aH1, rs1)
        DOTQ(22, aL2, aH2, rs0) DOTQ(23, aL3, aH3, rs1)
        DOTQ(24, aL0, aH0, rs0)
#undef DOTQ
        // group 25: k=100,101 real; slots 102,103 are constant 0 (safe in R)
        {
            f32x4 qv25 = P4[25];
            rs1 += qv25;
            aL1 = __builtin_elementwise_fma(
                m25a, (f32x2){qv25[0], qv25[1]}, aL1);
        }

        // ---- R from own reads: off the critical path (ready before dots) ----
        f32x4 rs = rs0 + rs1;
        float R = (rs[0] + rs[1]) + (rs[2] + rs[3]);
        R = fmaxf(R, 1e-30f);
        float invRs = __builtin_amdgcn_rcpf(R) * 0.00390625f;  // rcp(R)*2^-8

        float ec = __expf(lgA + erm);      // E for this step (lgA loaded t-3)

        f32x2 tL = (aL0 + aL1) + (aL2 + aL3);
        f32x2 tH = (aH0 + aH1) + (aH2 + aH3);
        f32x2 tt = tL + tH;
        float dot = tt[0] + tt[1];

        q = (dot * ec) * invRs;            // inactive lanes: ec=0 => q=0
        if (active) Qbuf[cur ^ 1][r] = q;

        __syncthreads();                   // writes visible; reads drained

        // ---- post-barrier shadow: overlaps next step's read latency ----
        Lacc += __log2f(R);
        lgA = lgB; lgB = lgC;
        lgC = lgp[(size_t)min(t + 3, T - 1) * CRF_L];
    }

    // ---- epilogue: out = ln2*(Lacc+8*len) + log(sum_j q_j exp(trans[STOP,j]))
    float tsr = trans[CRF_L * CRF_STOP + (active ? r : 0)];
    float e;
    if (len == 0) {
        e = (active && r == CRF_START) ? __expf(tsr) : 0.f;  // Q0=onehot
    } else {
        e = q * __expf(tsr);               // inactive lanes: q=0
    }
    float sw = wave_sum64(e);
    if (lane == 0) Qbuf[0][wv] = sw;
    __syncthreads();
    if (tid == 0)
        out[b] = LN2F * (Lacc + 8.0f * (float)len)
               + __logf(Qbuf[0][0] + Qbuf[0][1]);
}

extern "C" void kernel_launch(void* const* d_in, const int* in_sizes, int n_in,
                              void* d_out, int out_size, void* d_ws, size_t ws_size,
                              hipStream_t stream) {
    const float* logits = (const float*)d_in[0];   // [B, T, L] fp32
    const float* trans  = (const float*)d_in[1];   // [L, L] fp32
    const int*   lens   = (const int*)d_in[2];     // [B] int32
    float* out = (float*)d_out;                    // [B] fp32

    const int B = 512;
    const int T = 512;

    crf_forward_kernel<<<dim3(B), dim3(128), 0, stream>>>(
        logits, trans, lens, out, B, T);
}

// Round 8
// 579.018 us; speedup vs baseline: 1.0333x; 1.0333x over previous
//
#include <hip/hip_runtime.h>

// CRF forward (partition fn), B=512, T=512, L=102 (start=100, stop=101).
// R15: consumer-side R, register-neutral (R14 post-mortem: +12 VGPR live
// state over R13's ~130 hit this compiler's ~132 ceiling -> scratch spill
// inside the fma chain; 265->487us. The idea was never fairly tested).
// Deltas vs R13, engineered to fit UNDER the budget:
//   1. R = sum q_{t-1} side-summed from each lane's own 26 b128 reads
//      (2x f32x2 chains, +4 VGPR; issue hides under read stalls).
//   2. Dot accumulators 8 -> 4 chains (-8 VGPR; depth 13, re-issue ~8cy
//      >= fma latency; R10 already showed chain count doesn't matter).
//   3. Exponent-trick scale: s_t = 2^-(e+8), e = exponent(R), integer
//      extraction. Removes rcp (was ON the q path) and __log2f; Lacc is
//      an exact int accumulate. Logged scale == applied scale, so the
//      recurrence is self-consistent; t=0 gives R=1 -> 2^-8 as before.
//   DPP tail + pad-S writes deleted. Net VGPR vs R13: -4.
// Serial path: 26 ds_read_b128 -> 51 pk_fma -> 2 mul -> ds_write -> barrier.
// Verification handles: VGPR <=132 (if ~480us -> consumer-R toxic, revert),
// LDS ~1KB, conflicts 0.

typedef float f32x2 __attribute__((ext_vector_type(2)));
typedef float f32x4 __attribute__((ext_vector_type(4)));

#define CRF_L 102
#define CRF_RP 104
#define CRF_START 100
#define CRF_STOP 101
#define NEG_BIG (-1.0e30f)
#define LN2F 0.6931471805599453f

#define REP25(X) X(0) X(1) X(2) X(3) X(4) X(5) X(6) X(7) X(8) X(9) X(10) \
                 X(11) X(12) X(13) X(14) X(15) X(16) X(17) X(18) X(19) \
                 X(20) X(21) X(22) X(23) X(24)

template <int CTRL>
__device__ __forceinline__ float dpp_add_step(float x) {
    int xi = __builtin_bit_cast(int, x);
    int yi = __builtin_amdgcn_update_dpp(0, xi, CTRL, 0xf, 0xf, true);
    return x + __builtin_bit_cast(float, yi);
}
__device__ __forceinline__ float wave_sum64(float v) {
    v = dpp_add_step<0x111>(v);  // row_shr:1
    v = dpp_add_step<0x112>(v);  // row_shr:2
    v = dpp_add_step<0x114>(v);  // row_shr:4
    v = dpp_add_step<0x118>(v);  // row_shr:8
    v = dpp_add_step<0x142>(v);  // row_bcast:15
    v = dpp_add_step<0x143>(v);  // row_bcast:31
    return __builtin_bit_cast(float,
        __builtin_amdgcn_readlane(__builtin_bit_cast(int, v), 63));
}

__device__ __forceinline__ f32x2 mk2f(const float* rowp, int k, float rmx) {
    float e0 = __expf(rowp[k + 0] - rmx);
    float e1 = __expf(rowp[k + 1] - rmx);
    return (f32x2){e0, e1};
}

__attribute__((amdgpu_waves_per_eu(1, 1)))
__launch_bounds__(128)
__global__ void crf_forward_kernel(const float* __restrict__ logits,
                                   const float* __restrict__ trans,
                                   const int* __restrict__ lens,
                                   float* __restrict__ out,
                                   int B, int T) {
    const int b    = blockIdx.x;
    const int tid  = threadIdx.x;          // 0..127
    const int wv   = tid >> 6;             // wave 0/1
    const int lane = tid & 63;
    const bool active = (lane < 51);
    const int r    = 51 * wv + lane;       // row 0..101 for active lanes

    // Q double-buffer: [p][0..101] = q values; [p][102],[103] = 0 (constant)
    __shared__ __align__(16) float Qbuf[2][CRF_RP];

    // ---- init Qbuf[0] = onehot(START); pads of BOTH buffers = 0 ----
    if (tid < 51) {
        int i0 = 2 * tid;
        Qbuf[0][i0]     = (i0 == CRF_START) ? 1.f : 0.f;
        Qbuf[0][i0 + 1] = 0.f;
    }
    if (tid == 0) {
        Qbuf[0][102] = 0.f; Qbuf[0][103] = 0.f;
        Qbuf[1][102] = 0.f; Qbuf[1][103] = 0.f;
    }

    // ---- per-lane row of Mhat = exp(trans[r,:] - rowmax) in 51 f32x2 regs --
    const float* rowp = trans + (size_t)CRF_L * (active ? r : 0);
    float rmx = NEG_BIG;
    #pragma unroll
    for (int k = 0; k < CRF_L; ++k) rmx = fmaxf(rmx, rowp[k]);

#define DECLM(j) f32x2 m##j##a, m##j##b;
    REP25(DECLM)
#undef DECLM
    f32x2 m25a;
#define PACKJ(j) m##j##a = mk2f(rowp, 4*(j), rmx); \
                 m##j##b = mk2f(rowp, 4*(j)+2, rmx);
    REP25(PACKJ)
#undef PACKJ
    m25a = mk2f(rowp, 100, rmx);           // k = 100,101 (pads have no coeff)

    // E = exp(logit + rmx); inactive lanes forced to 0 via -inf bias
    const float erm = active ? rmx : NEG_BIG;

    const int len = min(lens[b], T);
    const float* lgp = logits + (size_t)b * (size_t)T * (size_t)CRF_L
                              + (active ? r : 0);

    // depth-3 scalar logit prefetch
    float lgA = lgp[0];
    float lgB = lgp[(size_t)min(1, T - 1) * CRF_L];
    float lgC = lgp[(size_t)min(2, T - 1) * CRF_L];

    float q   = 0.f;
    int  eacc = 0;                         // sum of exponent fields of R

    __syncthreads();                       // init visible to both waves

    for (int t = 0; t < len; ++t) {
        const int cur = t & 1;
        const f32x4* P4 = reinterpret_cast<const f32x4*>(&Qbuf[cur][0]);

        // ---- dot(Mhat[r,:], Q) + side-sum R from the same 26 b128 reads ----
        f32x2 aL0 = {0.f,0.f}, aL1 = {0.f,0.f};
        f32x2 aH0 = {0.f,0.f}, aH1 = {0.f,0.f};
        f32x2 rs0 = {0.f,0.f}, rs1 = {0.f,0.f};
#define DOTQ(j, AL, AH) { f32x4 qv_ = P4[j]; \
        f32x2 qlo_ = (f32x2){qv_[0], qv_[1]}; \
        f32x2 qhi_ = (f32x2){qv_[2], qv_[3]}; \
        rs0 += qlo_; rs1 += qhi_; \
        AL = __builtin_elementwise_fma(m##j##a, qlo_, AL); \
        AH = __builtin_elementwise_fma(m##j##b, qhi_, AH); }
        DOTQ(0,  aL0, aH0) DOTQ(1,  aL1, aH1)
        DOTQ(2,  aL0, aH0) DOTQ(3,  aL1, aH1)
        DOTQ(4,  aL0, aH0) DOTQ(5,  aL1, aH1)
        DOTQ(6,  aL0, aH0) DOTQ(7,  aL1, aH1)
        DOTQ(8,  aL0, aH0) DOTQ(9,  aL1, aH1)
        DOTQ(10, aL0, aH0) DOTQ(11, aL1, aH1)
        DOTQ(12, aL0, aH0) DOTQ(13, aL1, aH1)
        DOTQ(14, aL0, aH0) DOTQ(15, aL1, aH1)
        DOTQ(16, aL0, aH0) DOTQ(17, aL1, aH1)
        DOTQ(18, aL0, aH0) DOTQ(19, aL1, aH1)
        DOTQ(20, aL0, aH0) DOTQ(21, aL1, aH1)
        DOTQ(22, aL0, aH0) DOTQ(23, aL1, aH1)
        DOTQ(24, aL0, aH0)
#undef DOTQ
        // group 25: k=100,101 real; slots 102,103 constant 0 (safe in rs)
        {
            f32x4 qv25 = P4[25];
            f32x2 qlo_ = (f32x2){qv25[0], qv25[1]};
            rs0 += qlo_;
            rs1 += (f32x2){qv25[2], qv25[3]};
            aL1 = __builtin_elementwise_fma(m25a, qlo_, aL1);
        }

        // ---- R -> power-of-two scale via exponent extraction (int ops) ----
        f32x2 rsv = rs0 + rs1;
        float R = fmaxf(rsv[0] + rsv[1], 1.175494351e-38f);  // normal min
        int ef = __builtin_bit_cast(int, R) >> 23;   // exponent field (R>0)
        float invRs = __builtin_bit_cast(float, (246 - ef) << 23); // 2^-(e+8)
        eacc += ef;

        float ec = __expf(lgA + erm);      // E for this step (lgA loaded t-3)

        f32x2 tt = (aL0 + aL1) + (aH0 + aH1);
        float dot = tt[0] + tt[1];

        q = (dot * ec) * invRs;            // inactive lanes: ec=0 => q=0
        if (active) Qbuf[cur ^ 1][r] = q;

        // shadow (pre-barrier, off the LDS path): prefetch rotate
        lgA = lgB; lgB = lgC;
        lgC = lgp[(size_t)min(t + 3, T - 1) * CRF_L];

        __syncthreads();                   // writes visible; reads drained
    }

    // ---- epilogue ----
    // scale logged per step: e_t + 8, e_t = ef_t - 127
    // out = ln2 * (eacc - 119*len) + log(sum_j q_j exp(trans[STOP,j]))
    float tsr = trans[CRF_L * CRF_STOP + (active ? r : 0)];
    float e;
    if (len == 0) {
        e = (active && r == CRF_START) ? __expf(tsr) : 0.f;  // Q0=onehot
    } else {
        e = q * __expf(tsr);               // inactive lanes: q=0
    }
    float sw = wave_sum64(e);
    if (lane == 0) Qbuf[0][wv] = sw;
    __syncthreads();
    if (tid == 0)
        out[b] = LN2F * ((float)eacc - 119.0f * (float)len)
               + __logf(Qbuf[0][0] + Qbuf[0][1]);
}

extern "C" void kernel_launch(void* const* d_in, const int* in_sizes, int n_in,
                              void* d_out, int out_size, void* d_ws, size_t ws_size,
                              hipStream_t stream) {
    const float* logits = (const float*)d_in[0];   // [B, T, L] fp32
    const float* trans  = (const float*)d_in[1];   // [L, L] fp32
    const int*   lens   = (const int*)d_in[2];     // [B] int32
    float* out = (float*)d_out;                    // [B] fp32

    const int B = 512;
    const int T = 512;

    crf_forward_kernel<<<dim3(B), dim3(128), 0, stream>>>(
        logits, trans, lens, out, B, T);
}